// Round 12
// baseline (1173.043 us; speedup 1.0000x reference)
//
#include <hip/hip_runtime.h>

#define T_DIM 4096
#define K1    4096      // H (hidden)
#define I_DIM 11008
#define QMAXF 127.0f

typedef int v4i  __attribute__((ext_vector_type(4)));
typedef int v16i __attribute__((ext_vector_type(16)));

// ---------------- helpers ----------------

__device__ __forceinline__ void gload16(const void* g, void* l) {
  __builtin_amdgcn_global_load_lds((__attribute__((address_space(1))) unsigned int*)(g),
                                   (__attribute__((address_space(3))) unsigned int*)(l),
                                   16, 0, 0);
}

__device__ __forceinline__ int packq(float a, float b, float c, float d) {
  return ((int)a & 255) | (((int)b & 255) << 8) | (((int)c & 255) << 16) | (((int)d & 255) << 24);
}

#define MFMA32(A, B, C) __builtin_amdgcn_mfma_i32_32x32x32_i8(A, B, C, 0, 0, 0)

// ---------------- pass 1: absmax(x) ----------------

__global__ void absmax_x_kernel(const float4* __restrict__ x4, unsigned* __restrict__ maxbits, int n4) {
  int tid = blockIdx.x * blockDim.x + threadIdx.x;
  int stride = gridDim.x * blockDim.x;
  float m = 0.f;
  for (int i = tid; i < n4; i += stride) {
    float4 v = x4[i];
    m = fmaxf(m, fmaxf(fmaxf(fabsf(v.x), fabsf(v.y)), fmaxf(fabsf(v.z), fabsf(v.w))));
  }
  #pragma unroll
  for (int off = 32; off; off >>= 1) m = fmaxf(m, __shfl_xor(m, off));
  if ((threadIdx.x & 63) == 0) atomicMax(maxbits, __float_as_uint(m));
}

// ---------------- pass 2: quantize x ----------------

__global__ void quant_x_kernel(const float4* __restrict__ x4, v4i* __restrict__ q4,
                               const unsigned* __restrict__ scal) {
  const float sx = __uint_as_float(scal[0]) * (1.0f / QMAXF);
  const long i = (long)blockIdx.x * blockDim.x + threadIdx.x;  // 16 floats per thread
  v4i o;
  #pragma unroll
  for (int j = 0; j < 4; ++j) {
    float4 v = x4[i * 4 + j];
    float a = fminf(fmaxf(rintf(v.x / sx), -QMAXF), QMAXF);
    float b = fminf(fmaxf(rintf(v.y / sx), -QMAXF), QMAXF);
    float c = fminf(fmaxf(rintf(v.z / sx), -QMAXF), QMAXF);
    float d = fminf(fmaxf(rintf(v.w / sx), -QMAXF), QMAXF);
    o[j] = packq(a, b, c, d);
  }
  q4[i] = o;
}

// ---------------- weight f32(int-valued) -> int8 ----------------

__global__ void conv_w_kernel(const float4* __restrict__ w4, v4i* __restrict__ q4) {
  const long i = (long)blockIdx.x * blockDim.x + threadIdx.x;  // 16 floats per thread
  v4i o;
  #pragma unroll
  for (int j = 0; j < 4; ++j) {
    float4 v = w4[i * 4 + j];
    o[j] = packq(rintf(v.x), rintf(v.y), rintf(v.z), rintf(v.w));
  }
  q4[i] = o;
}

// ================= R5 schedule with BK=128, ring-2 =================
// 256x256 tile, BK=128. LDS per buffer: A [kslot:8][256 rows][16B] at 0 (32 KB),
// B same at 32768 -> 64 KB/buf, 2 buffers = 128 KB.
// 8 waves (4M x 2N), per-wave 64 rows x 128 staged cols, acc[2][4] v16i (unchanged from R5).
// Per tile: top {vmcnt(0) covered-drain; barrier}, then 2 phases:
//   phase0 (kslots 0..3): 12 ds_read; stage A of t+1 (4 gloads); barrier; lgkm0;
//                         sched_barrier; prio1; 16 MFMA; prio0
//   phase1 (kslots 4..7): same with B staging.
// Ring-2 race check: buf (t+1)&1's last reads happened in tile t-1, whose lgkm0s
// precede tile t's top barrier; staging issues after that barrier. Sync points per
// 128 K: 3 (vs 6 in R5) -- amortizes the measured ~2400 cy/tile convoy cost.

#define STG_A4(KO, LS) {                                                    \
    gload16(gA + (KO),      &LS[lA]);                                       \
    gload16(gA + (KO) + 32, &LS[lA + 8192]);                                \
    gload16(gA + (KO) + 64, &LS[lA + 16384]);                               \
    gload16(gA + (KO) + 96, &LS[lA + 24576]);                               \
  }
#define STG_B4(KO, LS) {                                                    \
    gload16(gB + (KO),      &LS[lB]);                                       \
    gload16(gB + (KO) + 32, &LS[lB + 8192]);                                \
    gload16(gB + (KO) + 64, &LS[lB + 16384]);                               \
    gload16(gB + (KO) + 96, &LS[lB + 24576]);                               \
  }

// one phase: base kslot pair KS0 (0 or 4); reads + optional stage + sync + 16 MFMA
#define PHASE(KS0, STMT_STAGE)                                              \
  {                                                                         \
    v4i a00 = *(const v4i*)&Lb[(KS0 + kgl) * 4096 + ab];                    \
    v4i a01 = *(const v4i*)&Lb[(KS0 + kgl) * 4096 + ab + 512];              \
    v4i b00 = *(const v4i*)&Lb[(KS0 + kgl) * 4096 + bb];                    \
    v4i b01 = *(const v4i*)&Lb[(KS0 + kgl) * 4096 + bb + 512];              \
    v4i b02 = *(const v4i*)&Lb[(KS0 + kgl) * 4096 + bb + 1024];             \
    v4i b03 = *(const v4i*)&Lb[(KS0 + kgl) * 4096 + bb + 1536];             \
    v4i a10 = *(const v4i*)&Lb[(KS0 + 2 + kgl) * 4096 + ab];                \
    v4i a11 = *(const v4i*)&Lb[(KS0 + 2 + kgl) * 4096 + ab + 512];          \
    v4i b10 = *(const v4i*)&Lb[(KS0 + 2 + kgl) * 4096 + bb];                \
    v4i b11 = *(const v4i*)&Lb[(KS0 + 2 + kgl) * 4096 + bb + 512];          \
    v4i b12 = *(const v4i*)&Lb[(KS0 + 2 + kgl) * 4096 + bb + 1024];         \
    v4i b13 = *(const v4i*)&Lb[(KS0 + 2 + kgl) * 4096 + bb + 1536];         \
    STMT_STAGE                                                              \
    __builtin_amdgcn_s_barrier();                                           \
    asm volatile("s_waitcnt lgkmcnt(0)" ::: "memory");                      \
    __builtin_amdgcn_sched_barrier(0);                                      \
    __builtin_amdgcn_s_setprio(1);                                          \
    acc[0][0] = MFMA32(a00, b00, acc[0][0]);                                \
    acc[0][1] = MFMA32(a00, b01, acc[0][1]);                                \
    acc[0][2] = MFMA32(a00, b02, acc[0][2]);                                \
    acc[0][3] = MFMA32(a00, b03, acc[0][3]);                                \
    acc[1][0] = MFMA32(a01, b00, acc[1][0]);                                \
    acc[1][1] = MFMA32(a01, b01, acc[1][1]);                                \
    acc[1][2] = MFMA32(a01, b02, acc[1][2]);                                \
    acc[1][3] = MFMA32(a01, b03, acc[1][3]);                                \
    acc[0][0] = MFMA32(a10, b10, acc[0][0]);                                \
    acc[0][1] = MFMA32(a10, b11, acc[0][1]);                                \
    acc[0][2] = MFMA32(a10, b12, acc[0][2]);                                \
    acc[0][3] = MFMA32(a10, b13, acc[0][3]);                                \
    acc[1][0] = MFMA32(a11, b10, acc[1][0]);                                \
    acc[1][1] = MFMA32(a11, b11, acc[1][1]);                                \
    acc[1][2] = MFMA32(a11, b12, acc[1][2]);                                \
    acc[1][3] = MFMA32(a11, b13, acc[1][3]);                                \
    __builtin_amdgcn_s_setprio(0);                                          \
  }

#define KLOOP(NK)                                                           \
  for (int t = 0; t < (NK); ++t) {                                          \
    asm volatile("s_waitcnt vmcnt(0)" ::: "memory");                        \
    __builtin_amdgcn_s_barrier();                                           \
    asm volatile("" ::: "memory");                                          \
    const signed char* Lb = L[t & 1];                                       \
    signed char* Ls = L[(t + 1) & 1];                                       \
    const bool st = (t + 1) < (NK);                                         \
    const int ko = (t + 1) * 128;                                           \
    PHASE(0, if (st) STG_A4(ko, Ls))                                        \
    PHASE(4, if (st) STG_B4(ko, Ls))                                        \
  }

// ---------------- GEMM1 fused: int8 GEMM + dequant + silu*mul + h absmax ----------------

__global__ __launch_bounds__(512, 2)
void gemm1_silu_kernel(const signed char* __restrict__ qx,
                       const signed char* __restrict__ w8,
                       const float* __restrict__ sgu,
                       unsigned* __restrict__ scal,
                       float* __restrict__ hbuf)
{
  __shared__ signed char L[2][65536];   // per buf: A [0,32768), B [32768,65536)

  const int tid  = threadIdx.x;
  const int lane = tid & 63;
  const int wid  = tid >> 6;       // 0..7
  const int wr   = wid >> 1;       // 0..3  (64-row band)
  const int wc   = wid & 1;        // 0..1  (128 staged-B rows)
  const int l31  = lane & 31;
  const int kgl  = lane >> 5;

  // XCD-chunked bijective swizzle (1376 = 8*172); brow fastest -> B panel L2-resident
  const int lin = blockIdx.x;
  const int sw  = (lin & 7) * 172 + (lin >> 3);
  const int brow = (sw & 15) * 256;
  const int bcol = (sw >> 4) * 128;            // h-col base (128 per block)

  // staging: thread covers staged row sr=tid&255, base sub-kslot sk=tid>>8; kslots sk+2j
  const int sr = tid & 255, sk = tid >> 8;
  const signed char* gA = qx + (size_t)(brow + sr) * K1 + sk * 16;
  const int grp = sr >> 6, w = sr & 63;
  const int gcolw = bcol + grp * 32 + (w & 31);
  const size_t srcrow = (w < 32) ? (size_t)gcolw : (size_t)(I_DIM + gcolw);
  const signed char* gB = w8 + srcrow * K1 + sk * 16;
  const int lA = tid * 16;             // = sk*4096 + sr*16; + j*8192 per kslot pair
  const int lB = 32768 + tid * 16;

  const int ab = (wr * 64 + l31) * 16;
  const int bb = 32768 + (wc * 128 + l31) * 16;

  v16i zero = {0};
  v16i acc[2][4];
  #pragma unroll
  for (int m = 0; m < 2; ++m)
    #pragma unroll
    for (int n = 0; n < 4; ++n) acc[m][n] = zero;

  const int nk = K1 / 128;  // 32
  // prologue: stage tile 0 -> buf0
  STG_A4(0, L[0]);
  STG_B4(0, L[0]);

  KLOOP(nk)

  // epilogue: dequant + silu*mul, write h, track max|h|
  // C layout (32x32): col(lane)=l31, row = (q&3) + 8*(q>>2) + 4*kgl
  // n-frag pairs: (0,1)=gate/up @ grp wc*2, (2,3)=gate/up @ grp wc*2+1
  const float xsc = __uint_as_float(scal[0]) * (1.0f / QMAXF);
  float hmax = 0.f;
  #pragma unroll
  for (int m = 0; m < 2; ++m) {
    const int rbase = brow + wr * 64 + m * 32 + 4 * kgl;
    #pragma unroll
    for (int p = 0; p < 2; ++p) {
      const int col = bcol + (wc * 2 + p) * 32 + l31;
      const float sg = sgu[col] * xsc;
      const float su = sgu[I_DIM + col] * xsc;
      #pragma unroll
      for (int q = 0; q < 16; ++q) {
        const int row = rbase + (q & 3) + 8 * (q >> 2);
        float g = (float)acc[m][2 * p][q] * sg;
        float u = (float)acc[m][2 * p + 1][q] * su;
        float hv = (g / (1.f + expf(-g))) * u;
        hmax = fmaxf(hmax, fabsf(hv));
        hbuf[(size_t)row * I_DIM + col] = hv;
      }
    }
  }
  #pragma unroll
  for (int off = 32; off; off >>= 1) hmax = fmaxf(hmax, __shfl_xor(hmax, off));
  if (lane == 0) atomicMax(scal + 1, __float_as_uint(hmax));
}

// ---------------- quantize h (+ emit h_scale) ----------------

__global__ void quant_h_kernel(const float4* __restrict__ h4, v4i* __restrict__ q4,
                               const unsigned* __restrict__ scal, float* __restrict__ hs_out) {
  const float hs = __uint_as_float(scal[1]) * (1.0f / QMAXF);
  const long i = (long)blockIdx.x * blockDim.x + threadIdx.x;
  if (i == 0) hs_out[0] = hs;
  v4i o;
  #pragma unroll
  for (int j = 0; j < 4; ++j) {
    float4 v = h4[i * 4 + j];
    float a = fminf(fmaxf(rintf(v.x / hs), -QMAXF), QMAXF);
    float b = fminf(fmaxf(rintf(v.y / hs), -QMAXF), QMAXF);
    float c = fminf(fmaxf(rintf(v.z / hs), -QMAXF), QMAXF);
    float d = fminf(fmaxf(rintf(v.w / hs), -QMAXF), QMAXF);
    o[j] = packq(a, b, c, d);
  }
  q4[i] = o;
}

// ---------------- GEMM2: out = (qh @ wdn^T) * (h_scale * s_down) ----------------
// 256x256 tile, BK=128, nk=86, same structure. Grid 256 = 1 block/CU.

__global__ __launch_bounds__(512, 2)
void gemm2_kernel(const signed char* __restrict__ qh,
                  const signed char* __restrict__ w8,
                  const float* __restrict__ sdn,
                  const unsigned* __restrict__ scal,
                  float* __restrict__ out)
{
  __shared__ signed char L[2][65536];

  const int tid  = threadIdx.x;
  const int lane = tid & 63;
  const int wid  = tid >> 6;
  const int wr   = wid >> 1;       // 0..3
  const int wc   = wid & 1;        // 0..1
  const int l31  = lane & 31;
  const int kgl  = lane >> 5;

  const int lin = blockIdx.x;                  // 0..255 = 8*32
  const int sw  = (lin & 7) * 32 + (lin >> 3);
  const int brow = (sw & 15) * 256;
  const int bcol = (sw >> 4) * 256;

  const int sr = tid & 255, sk = tid >> 8;
  const signed char* gA = qh + (size_t)(brow + sr) * I_DIM + sk * 16;
  const signed char* gB = w8 + (size_t)(bcol + sr) * I_DIM + sk * 16;
  const int lA = tid * 16;
  const int lB = 32768 + tid * 16;

  const int ab = (wr * 64 + l31) * 16;
  const int bb = 32768 + (wc * 128 + l31) * 16;

  v16i zero = {0};
  v16i acc[2][4];
  #pragma unroll
  for (int m = 0; m < 2; ++m)
    #pragma unroll
    for (int n = 0; n < 4; ++n) acc[m][n] = zero;

  const int nk = I_DIM / 128;  // 86
  STG_A4(0, L[0]);
  STG_B4(0, L[0]);

  KLOOP(nk)

  const float hsc = __uint_as_float(scal[1]) * (1.0f / QMAXF);
  #pragma unroll
  for (int m = 0; m < 2; ++m) {
    const int rbase = brow + wr * 64 + m * 32 + 4 * kgl;
    #pragma unroll
    for (int n = 0; n < 4; ++n) {
      const int col = bcol + wc * 128 + n * 32 + l31;
      const float s = sdn[col] * hsc;
      #pragma unroll
      for (int q = 0; q < 16; ++q) {
        const int row = rbase + (q & 3) + 8 * (q >> 2);
        out[(size_t)row * K1 + col] = (float)acc[m][n][q] * s;
      }
    }
  }
}

// ---------------- launch ----------------

extern "C" void kernel_launch(void* const* d_in, const int* in_sizes, int n_in,
                              void* d_out, int out_size, void* d_ws, size_t ws_size,
                              hipStream_t stream) {
  (void)in_sizes; (void)n_in; (void)out_size; (void)ws_size;
  const float* x   = (const float*)d_in[0];
  const float* wgu = (const float*)d_in[1];
  const float* sgu = (const float*)d_in[2];
  const float* wdn = (const float*)d_in[3];
  const float* sdn = (const float*)d_in[4];
  float* out = (float*)d_out;
  char* ws = (char*)d_ws;

  // ws layout (16B aligned): total ~360 MB
  signed char* qx  = (signed char*)(ws + 0LL);           // 16,777,216
  signed char* w8g = (signed char*)(ws + 16777216LL);    // 90,177,536
  signed char* w8d = (signed char*)(ws + 106954752LL);   // 45,088,768
  signed char* qh  = (signed char*)(ws + 152043520LL);   // 45,088,768
  float*       hb  = (float*)      (ws + 197132288LL);   // 180,355,072
  unsigned*    scal= (unsigned*)   (ws + 377487360LL);   // 256

  hipMemsetAsync(scal, 0, 256, stream);
  absmax_x_kernel<<<2048, 256, 0, stream>>>((const float4*)x, scal, T_DIM * K1 / 4);
  quant_x_kernel<<<4096, 256, 0, stream>>>((const float4*)x, (v4i*)qx, scal);
  conv_w_kernel<<<22016, 256, 0, stream>>>((const float4*)wgu, (v4i*)w8g);
  conv_w_kernel<<<11008, 256, 0, stream>>>((const float4*)wdn, (v4i*)w8d);

  gemm1_silu_kernel<<<1376, 512, 0, stream>>>(qx, w8g, sgu, scal, hb);

  quant_h_kernel<<<11008, 256, 0, stream>>>((const float4*)hb, (v4i*)qh, scal,
                                            out + (size_t)T_DIM * K1);

  gemm2_kernel<<<256, 512, 0, stream>>>(qh, w8d, sdn, scal, out);
}